// Round 1
// baseline (2668.122 us; speedup 1.0000x reference)
//
#include <hip/hip_runtime.h>
#include <hip/hip_bf16.h>

#define B_   32
#define T_   512
#define H_   1024
#define L_   256
#define V_   13
#define G4H  4096
#define KHL  1280   // H + L

typedef float f32x4 __attribute__((ext_vector_type(4)));
typedef short s16x8 __attribute__((ext_vector_type(8)));
typedef unsigned short u16;
typedef unsigned int   u32;

// ---------------- ws layout (bytes) ----------------
// hsb : u16 [513][32][1024]   @ 0           (33,619,968)  h chain, slot 0 = h0
// cbuf: f32 [32][1024]        @ 33,619,968  (131,072)
// Bf  : u16 [4,194,304]       @ 33,751,040  (8,388,608)   W_hh MFMA B-fragments
// Bf2 : u16 [1,310,720]       @ 42,139,648  (2,621,440)   Wnl  MFMA B-fragments
// bias: f32 [4096]            @ 44,761,088  (16,384)      b_ih + b_hh
// zbuf: u16 [32][256]         @ 44,777,472  (16,384)      latent bf16
// mid : u16 [16384][1024]     @ 44,793,856  (33,554,432)  relu(feat@Wnl^T+bnl)
// total ~78.3 MB
#define OFF_CBUF 33619968u
#define OFF_BF   33751040u
#define OFF_BF2  42139648u
#define OFF_BIAS 44761088u
#define OFF_ZBUF 44777472u
#define OFF_MID  44793856u

__device__ __forceinline__ u16 f2bf(float f) {
    union { float f; u32 u; } v; v.f = f;
    u32 u = v.u;
    u32 r = (u + 0x7fffu + ((u >> 16) & 1u)) >> 16;   // RNE
    return (u16)r;
}
__device__ __forceinline__ float bf2f(u16 h) {
    union { u32 u; float f; } v; v.u = ((u32)h) << 16;
    return v.f;
}
__device__ __forceinline__ float sigm_(float x) {
    x = fminf(fmaxf(x, -30.f), 30.f);
    return 1.f / (1.f + __expf(-x));
}
__device__ __forceinline__ float tanh_(float x) {
    x = fminf(fmaxf(x, -15.f), 15.f);
    float e = __expf(2.f * x);
    return (e - 1.f) / (e + 1.f);
}

// ---------------------------------------------------------------------------
// init: h0 = relu(latent @ Wz^T + bz) -> hsb[0] (bf16); c=0; bias; zbuf
__global__ __launch_bounds__(256) void k_init_misc(
        const float* __restrict__ latent, const float* __restrict__ Wz,
        const float* __restrict__ bz, const float* __restrict__ b_ih,
        const float* __restrict__ b_hh,
        u16* __restrict__ hsb, float* __restrict__ cbuf,
        float* __restrict__ bias, u16* __restrict__ zbuf) {
    int gid = blockIdx.x * 256 + threadIdx.x;          // [0, 32768)
    int b = gid >> 10, j = gid & 1023;
    const float* lrow = latent + b * L_;
    const float* wrow = Wz + j * L_;
    float acc = bz[j];
    #pragma unroll 4
    for (int l = 0; l < L_; ++l) acc += lrow[l] * wrow[l];
    hsb[gid] = f2bf(fmaxf(acc, 0.f));
    cbuf[gid] = 0.f;
    if (gid < G4H) bias[gid] = b_ih[gid] + b_hh[gid];
    if (gid < B_ * L_) zbuf[gid] = f2bf(latent[gid]);
}

// W_hh -> MFMA B fragments, column-interleaved so one 16-wide N-tile holds
// all 4 gates for 4 consecutive j. Linear idx == frag address:
// idx = (nt<<14)|(kc<<9)|(lane<<3)|jv ; n-within-tile u=lane&15 -> gate=u>>2,
// jj=u&3, row = gate*H + nt*4+jj ; k = kc*32 + (lane>>4)*8 + jv
__global__ __launch_bounds__(256) void k_init_wfrag(
        const float* __restrict__ W_hh, u16* __restrict__ Bf) {
    int base = blockIdx.x * 256 + threadIdx.x;         // 2048 blocks
    #pragma unroll
    for (int i = 0; i < 8; ++i) {
        int idx = base + i * 524288;                   // [0, 4194304)
        int jv   = idx & 7;
        int lane = (idx >> 3) & 63;
        int kc   = (idx >> 9) & 31;
        int nt   = idx >> 14;
        int u = lane & 15;
        int row = (u >> 2) * H_ + nt * 4 + (u & 3);
        int k = kc * 32 + (lane >> 4) * 8 + jv;
        Bf[idx] = f2bf(W_hh[row * H_ + k]);
    }
}

// Wnl -> MFMA B fragments: idx = ((nt2*40+kc)<<9)|(lane<<3)|jv
// n = nt2*16 + (lane&15), k = kc*32 + (lane>>4)*8 + jv, B[k][n] = Wnl[n][k]
__global__ __launch_bounds__(256) void k_init_wfrag2(
        const float* __restrict__ Wnl, u16* __restrict__ Bf2) {
    int idx = blockIdx.x * 256 + threadIdx.x;
    for (; idx < 1310720; idx += 524288) {
        int jv   = idx & 7;
        int lane = (idx >> 3) & 63;
        int q    = idx >> 9;                           // nt2*40 + kc
        int kc   = q % 40;
        int nt2  = q / 40;
        int n = nt2 * 16 + (lane & 15);
        int k = kc * 32 + (lane >> 4) * 8 + jv;
        Bf2[idx] = f2bf(Wnl[n * KHL + k]);
    }
}

// ---------------------------------------------------------------------------
// one LSTM step: gates = h_prev @ W_hh^T (MFMA) + x@W_ih^T + bias; c,h update.
// grid 256 x 128thr: bid&1 = m-tile (16 b's), bid>>1 picks 2 n-tiles (w=wave).
__global__ __launch_bounds__(128) void k_step(int s,
        const float* __restrict__ seq, const float* __restrict__ W_ih,
        const float* __restrict__ bias, const u16* __restrict__ Bf,
        u16* __restrict__ hsb, float* __restrict__ cbuf) {
    __shared__ u16 Ah[16][1032];          // +8 pad: 2-way-free LDS banks
    __shared__ float scr[2][16][17];      // [wave][u][b_local]
    int tid = threadIdx.x;
    int mt = blockIdx.x & 1;
    int bidn = blockIdx.x >> 1;           // [0,128)
    int m0 = mt * 16;

    const u16* hprev = hsb + (size_t)s * (B_ * H_) + m0 * H_;
    #pragma unroll
    for (int it = 0; it < 16; ++it) {
        int c = it * 128 + tid;           // [0,2048) chunks of 8 u16
        int row = c >> 7, col8 = c & 127;
        uint4 v = *reinterpret_cast<const uint4*>(hprev + row * H_ + col8 * 8);
        *reinterpret_cast<uint4*>(&Ah[row][col8 * 8]) = v;
    }
    __syncthreads();

    int w = tid >> 6, L = tid & 63;
    int nt = bidn * 2 + w;                // [0,256)
    int lm = L & 15, quad = L >> 4;
    const u16* ahp = &Ah[lm][quad * 8];
    const u16* bfp = Bf + (size_t)nt * 16384 + L * 8;
    f32x4 acc = {0.f, 0.f, 0.f, 0.f};
    #pragma unroll 4
    for (int kc = 0; kc < 32; ++kc) {
        s16x8 a = *reinterpret_cast<const s16x8*>(ahp + kc * 32);
        s16x8 bv = *reinterpret_cast<const s16x8*>(bfp + kc * 512);
        acc = __builtin_amdgcn_mfma_f32_16x16x32_bf16(a, bv, acc, 0, 0, 0);
    }
    #pragma unroll
    for (int r = 0; r < 4; ++r) scr[w][lm][quad * 4 + r] = acc[r];
    __syncthreads();

    // update: lane -> (b_local = L&15, jj = quad)
    int b = m0 + (L & 15);
    int jj = quad;
    int jg = nt * 4 + jj;
    const float* xrow = seq + (size_t)b * (T_ * V_) + s * V_;
    float xv[V_];
    #pragma unroll
    for (int v = 0; v < V_; ++v) xv[v] = xrow[v];
    float g[4];
    #pragma unroll
    for (int gg = 0; gg < 4; ++gg) {
        int row = gg * H_ + jg;
        float a = scr[w][gg * 4 + jj][L & 15] + bias[row];
        const float* wr = W_ih + row * V_;
        #pragma unroll
        for (int v = 0; v < V_; ++v) a += xv[v] * wr[v];
        g[gg] = a;
    }
    float ig = sigm_(g[0]), fg = sigm_(g[1]);
    float gt = tanh_(g[2]), og = sigm_(g[3]);
    float cv = fg * cbuf[b * H_ + jg] + ig * gt;
    cbuf[b * H_ + jg] = cv;
    float hv = og * tanh_(cv);
    hsb[(size_t)(s + 1) * (B_ * H_) + b * H_ + jg] = f2bf(hv);
}

// ---------------------------------------------------------------------------
// mid = relu(feat @ Wnl^T + bnl), feat=[hs|z], M=16384 (m=t*32+b), K=1280, N=1024
// block 256thr: tile M128 x N64 ; wave owns 32 rows x 64 cols (8 C-tiles)
__global__ __launch_bounds__(256) void k_gemm1(
        const u16* __restrict__ hsb, const u16* __restrict__ zbuf,
        const u16* __restrict__ Bf2, const float* __restrict__ bnl,
        u16* __restrict__ mid) {
    __shared__ u16 At[128][40];           // 32 k + 8 pad
    int tid = threadIdx.x;
    int nb = blockIdx.x;                  // [0,16)
    int mb = blockIdx.y;                  // [0,128)
    int w = tid >> 6, L = tid & 63;
    int lm = L & 15, quad = L >> 4;
    f32x4 acc[2][4];
    #pragma unroll
    for (int a = 0; a < 2; ++a)
        #pragma unroll
        for (int n = 0; n < 4; ++n) acc[a][n] = (f32x4){0.f, 0.f, 0.f, 0.f};

    for (int kc = 0; kc < 40; ++kc) {
        int k0 = kc * 32;
        #pragma unroll
        for (int it = 0; it < 2; ++it) {
            int c = it * 256 + tid;       // [0,512)
            int row = c >> 2, seg = c & 3;
            int m = mb * 128 + row;
            int k = k0 + seg * 8;
            uint4 v;
            if (k < 1024)
                v = *reinterpret_cast<const uint4*>(hsb + (size_t)(B_ * H_) + (size_t)m * H_ + k);
            else
                v = *reinterpret_cast<const uint4*>(zbuf + (row & 31) * L_ + (k - 1024));
            *reinterpret_cast<uint4*>(&At[row][seg * 8]) = v;
        }
        __syncthreads();
        s16x8 a0 = *reinterpret_cast<const s16x8*>(&At[w * 32 + lm][quad * 8]);
        s16x8 a1 = *reinterpret_cast<const s16x8*>(&At[w * 32 + 16 + lm][quad * 8]);
        const u16* bp = Bf2 + ((size_t)(nb * 4) * 40 + kc) * 512 + L * 8;
        #pragma unroll
        for (int n4 = 0; n4 < 4; ++n4) {
            s16x8 bv = *reinterpret_cast<const s16x8*>(bp + (size_t)n4 * 40 * 512);
            acc[0][n4] = __builtin_amdgcn_mfma_f32_16x16x32_bf16(a0, bv, acc[0][n4], 0, 0, 0);
            acc[1][n4] = __builtin_amdgcn_mfma_f32_16x16x32_bf16(a1, bv, acc[1][n4], 0, 0, 0);
        }
        __syncthreads();
    }
    #pragma unroll
    for (int mt2 = 0; mt2 < 2; ++mt2)
        #pragma unroll
        for (int n4 = 0; n4 < 4; ++n4)
            #pragma unroll
            for (int r = 0; r < 4; ++r) {
                int m = mb * 128 + w * 32 + mt2 * 16 + quad * 4 + r;
                int n = (nb * 4 + n4) * 16 + lm;
                float v = acc[mt2][n4][r] + bnl[n];
                mid[(size_t)m * H_ + n] = f2bf(fmaxf(v, 0.f));
            }
}

// ---------------------------------------------------------------------------
// logits = mid@Wout^T + bout (V=13); nll = lse - logit[label]; masked atomic acc
__global__ __launch_bounds__(256) void k_loss(
        const u16* __restrict__ mid, const float* __restrict__ Wout,
        const float* __restrict__ bout, const int* __restrict__ labels,
        const int* __restrict__ lengths, float* __restrict__ out) {
    int mrow = blockIdx.x;                // [0,16384) ; m = t*32 + b
    int b = mrow & 31, t = mrow >> 5;
    if (t >= lengths[b]) return;
    int tid = threadIdx.x;
    float p[V_];
    #pragma unroll
    for (int v = 0; v < V_; ++v) p[v] = 0.f;
    uint2 raw = *reinterpret_cast<const uint2*>(mid + (size_t)mrow * H_ + tid * 4);
    const u16* rs = (const u16*)&raw;
    float mv0 = bf2f(rs[0]), mv1 = bf2f(rs[1]), mv2 = bf2f(rs[2]), mv3 = bf2f(rs[3]);
    #pragma unroll
    for (int v = 0; v < V_; ++v) {
        float4 wv = *reinterpret_cast<const float4*>(Wout + v * H_ + tid * 4);
        p[v] = mv0 * wv.x + mv1 * wv.y + mv2 * wv.z + mv3 * wv.w;
    }
    #pragma unroll
    for (int off = 32; off > 0; off >>= 1)
        #pragma unroll
        for (int v = 0; v < V_; ++v) p[v] += __shfl_down(p[v], off);
    __shared__ float red[4][V_];
    int w = tid >> 6, L = tid & 63;
    if (L == 0)
        #pragma unroll
        for (int v = 0; v < V_; ++v) red[w][v] = p[v];
    __syncthreads();
    if (tid == 0) {
        float lg[V_]; float mx = -1e30f;
        #pragma unroll
        for (int v = 0; v < V_; ++v) {
            lg[v] = red[0][v] + red[1][v] + red[2][v] + red[3][v] + bout[v];
            mx = fmaxf(mx, lg[v]);
        }
        float se = 0.f;
        #pragma unroll
        for (int v = 0; v < V_; ++v) se += __expf(lg[v] - mx);
        float lse = mx + logf(se);
        int lab = labels[b * T_ + t];
        atomicAdd(&out[1 + b], lse - lg[lab]);
    }
}

__global__ void k_final(float* __restrict__ out) {
    float s = 0.f;
    for (int b = 0; b < B_; ++b) s += out[1 + b];
    out[0] = s;
}

// ---------------------------------------------------------------------------
extern "C" void kernel_launch(void* const* d_in, const int* in_sizes, int n_in,
                              void* d_out, int out_size, void* d_ws, size_t ws_size,
                              hipStream_t stream) {
    const float* seq    = (const float*)d_in[0];
    const float* latent = (const float*)d_in[1];
    const int*   labels = (const int*)d_in[2];
    const int*   lengths= (const int*)d_in[3];
    const float* W_ih   = (const float*)d_in[4];
    const float* W_hh   = (const float*)d_in[5];
    const float* b_ih   = (const float*)d_in[6];
    const float* b_hh   = (const float*)d_in[7];
    const float* Wz     = (const float*)d_in[8];
    const float* bz     = (const float*)d_in[9];
    const float* Wnl    = (const float*)d_in[10];
    const float* bnl    = (const float*)d_in[11];
    const float* Wout   = (const float*)d_in[12];
    const float* bout   = (const float*)d_in[13];

    char* ws = (char*)d_ws;
    u16*   hsb  = (u16*)(ws);
    float* cbuf = (float*)(ws + OFF_CBUF);
    u16*   Bf   = (u16*)(ws + OFF_BF);
    u16*   Bf2  = (u16*)(ws + OFF_BF2);
    float* bias = (float*)(ws + OFF_BIAS);
    u16*   zbuf = (u16*)(ws + OFF_ZBUF);
    u16*   mid  = (u16*)(ws + OFF_MID);
    float* out  = (float*)d_out;

    hipMemsetAsync(d_out, 0, 33 * sizeof(float), stream);
    k_init_misc<<<128, 256, 0, stream>>>(latent, Wz, bz, b_ih, b_hh, hsb, cbuf, bias, zbuf);
    k_init_wfrag<<<2048, 256, 0, stream>>>(W_hh, Bf);
    k_init_wfrag2<<<2048, 256, 0, stream>>>(Wnl, Bf2);
    for (int s = 0; s < T_; ++s)
        k_step<<<256, 128, 0, stream>>>(s, seq, W_ih, bias, Bf, hsb, cbuf);
    k_gemm1<<<dim3(16, 128), 256, 0, stream>>>(hsb, zbuf, Bf2, bnl, mid);
    k_loss<<<16384, 256, 0, stream>>>(mid, Wout, bout, labels, lengths, out);
    k_final<<<1, 1, 0, stream>>>(out);
}